// Round 12
// baseline (471.162 us; speedup 1.0000x reference)
//
#include <hip/hip_runtime.h>
#include <hip/hip_bf16.h>

typedef __hip_bfloat16 bf16;
typedef __attribute__((ext_vector_type(8))) short short8;
typedef __attribute__((ext_vector_type(4))) float f32x4;

#define B_  4
#define S_  1024
#define H_  16
#define R_  4096
#define LD_ 1088   // padded K / row stride for 1056-wide operands (mult of 64)

#define MBL 1048576L
// ---- workspace byte offsets (big path peak = 92 MiB; fallback peak = 60 MiB)
#define OFF_WQKVT (0L)
#define OFF_WOT   (6684672L)
#define OFF_X2    (0L)
#define OFF_W1T   (9L*MBL)
#define OFF_W2T   (18L*MBL)
#define OFF_BIAS  (26L*MBL)
#define OFF_XNB   (27L*MBL + MBL/2)
#define OFF_MCAT  OFF_XNB
#define OFF_HBUF  OFF_XNB
#define OFF_PART1 OFF_XNB          // W2 split-K z=1 partial (f32, 16 MiB);
                                   // XNB/ARAW dead by the time W2 runs.
                                   // 27.5+16=43.5 MiB < OFF_HHBIG (44 MiB).
#define OFF_QPS   (36L*MBL)
#define OFF_ARAW  OFF_QPS
#define OFF_KPS   (44L*MBL)
#define OFF_VT    (52L*MBL)
#define OFF_QT    (62L*MBL)
#define OFF_KT    (62L*MBL + 262144L)
#define OFF_HHBIG (44L*MBL)
#define OFF_MLPB  (76L*MBL)
#define OFF_HHC   (36L*MBL)
#define OFF_MLPF  (44L*MBL)
// bias block internal offsets (bytes from OFF_BIAS)
#define BQKV 0
#define BOF  16384
#define B1F  32768
#define B2F  65536
#define W2R0 81920
#define RCF  98304
#define RSNF 262144
#define SCLF 409600
#define TACC 425984
#define FLAG 458752

__device__ __forceinline__ bf16  f2bf(float v) { return __float2bfloat16(v); }
__device__ __forceinline__ float bf2f(bf16 v)  { return __bfloat162float(v); }
__device__ __forceinline__ unsigned short bf2s(float v) {
  return __builtin_bit_cast(unsigned short, __float2bfloat16(v));
}
__device__ __forceinline__ float ldu(const void* p, long i, int isbf) {
  return isbf ? bf2f(((const bf16*)p)[i]) : ((const float*)p)[i];
}
__device__ __forceinline__ void stu(void* p, long i, float v, int isbf) {
  if (isbf) ((bf16*)p)[i] = f2bf(v);
  else      ((float*)p)[i] = v;
}
__device__ __forceinline__ float gelu_f(float v) {
  const float u = 0.7978845608028654f * (v + 0.044715f * v * v * v);
  const float e = __expf(fminf(2.f * u, 80.f));
  return 0.5f * v * (1.f + (e - 1.f) / (e + 1.f));
}
__device__ __forceinline__ float bfu_lo(unsigned u) {
  return __builtin_bit_cast(float, u << 16);
}
__device__ __forceinline__ float bfu_hi(unsigned u) {
  return __builtin_bit_cast(float, u & 0xFFFF0000u);
}

// async global->LDS, 16B per lane. lds addr must equal wave-uniform base + lane*16.
__device__ __forceinline__ void gload16(const bf16* g, short* l) {
  __builtin_amdgcn_global_load_lds(
      (const __attribute__((address_space(1))) unsigned int*)g,
      (__attribute__((address_space(3))) unsigned int*)l, 16, 0, 0);
}

#define MFMA_(acc_, a_, b_) acc_ = __builtin_amdgcn_mfma_f32_16x16x32_bf16(a_, b_, acc_, 0, 0, 0)
// Read-completion guard: all of this wave's LDS reads done + reads cannot be
// reordered past this point (memory clobber). Does NOT touch vmcnt.
#define LGKM_GUARD() asm volatile("s_waitcnt lgkmcnt(0)" ::: "memory")
// DS-issue pin (null effect measured r6; kept, harmless).
#define DS_PIN() __builtin_amdgcn_sched_barrier(0x7F)

// Bijective chunked XCD swizzle (T1). Applied ONLY to mfma_gemm (W2/Wo):
// r7 measured FETCH 135->49 MB there. Not applied on gemm256/gemm_qkv256 —
// their operands are L3-fit, where swizzle costs ~2% (m160).
__device__ __forceinline__ void xcd_swz(int& bx, int& by) {
  const int nbx = gridDim.x;
  const int nb = nbx * gridDim.y;
  if ((nb & 7) == 0) {
    const int hid = blockIdx.y * nbx + blockIdx.x;
    const int l = (hid & 7) * (nb >> 3) + (hid >> 3);
    bx = l % nbx;
    by = l / nbx;
  } else {
    bx = blockIdx.x;
    by = blockIdx.y;
  }
}

__global__ void detect_kernel(const unsigned* __restrict__ g, int* __restrict__ flag) {
  if (threadIdx.x == 0) flag[0] = (g[0] == 0x3F803F80u) ? 1 : 0;
}

__global__ __launch_bounds__(256) void zero16_kernel(uint4* __restrict__ p, int n16) {
  int i = blockIdx.x * 256 + threadIdx.x;
  if (i < n16) p[i] = uint4{0, 0, 0, 0};
}

// block = 256 threads (4 waves)
__device__ __forceinline__ float bred_f(float v, float* sh) {
#pragma unroll
  for (int o = 32; o; o >>= 1) v += __shfl_xor(v, o);
  __syncthreads();
  if ((threadIdx.x & 63) == 0) sh[threadIdx.x >> 6] = v;
  __syncthreads();
  return sh[0] + sh[1] + sh[2] + sh[3];
}
__device__ __forceinline__ double bred_d(double v, double* sh) {
#pragma unroll
  for (int o = 32; o; o >>= 1) v += __shfl_xor(v, o);
  __syncthreads();
  if ((threadIdx.x & 63) == 0) sh[threadIdx.x >> 6] = v;
  __syncthreads();
  return sh[0] + sh[1] + sh[2] + sh[3];
}

// ---------------- mega_prep: prep_misc + 4 transposes + ln1, one dispatch
// block ranges: [0,297) misc | [297,1113) qkvT | [1113,1385) woT |
//               [1385,2473) w1T | [2473,3497) w2T | [3497,7593) ln1
__global__ __launch_bounds__(256) void mega_prep(
    const void* x, const void* rc, const void* rsn, const void* n1g, const void* n1b,
    const void* Wq, const void* bq, const void* Wk, const void* bk,
    const void* Wv, const void* bv, const void* scl, const void* ab,
    const void* Wo, const void* bo, const void* wr1,
    const void* W1, const void* b1, const void* W2, const void* b2, const void* wr2,
    char* bias_base, bf16* __restrict__ wqkvT, bf16* __restrict__ woT,
    bf16* __restrict__ w1T, bf16* __restrict__ w2T, bf16* __restrict__ xnb,
    const int* __restrict__ flag) {
  const int isbf = flag[0];
  __shared__ float tl[64][65];
  const int tid = threadIdx.x;
  int bid = blockIdx.x;
  if (bid < 297) {                       // ---- prep_misc ----
    int i = bid * 256 + tid;
    float* bqkvf = (float*)(bias_base + BQKV);
    if (i < 1024)        { bqkvf[i] = ldu(bq, i, isbf); return; }
    if (i < 2048)        { bqkvf[i] = ldu(bk, i - 1024, isbf); return; }
    if (i < 3072)        { bqkvf[i] = ldu(bv, i - 2048, isbf); return; }
    if (i < 4096)        { ((float*)(bias_base + BOF))[i - 3072] = ldu(bo, i - 3072, isbf); return; }
    if (i < 8192)        { ((float*)(bias_base + B1F))[i - 4096] = ldu(b1, i - 4096, isbf); return; }
    if (i < 9216)        { ((float*)(bias_base + B2F))[i - 8192] = ldu(b2, i - 8192, isbf); return; }
    if (i < 10240)       { ((float*)(bias_base + W2R0))[i - 9216] = ldu(W2, i - 9216, isbf); return; }
    if (i < 10240+32768) { ((float*)(bias_base + RCF))[i - 10240] = ldu(rc, i - 10240, isbf); return; }
    if (i < 10240+65536) { ((float*)(bias_base + RSNF))[i - 43008] = ldu(rsn, i - 43008, isbf); return; }
    if (i == 75776)      { ((float*)(bias_base + SCLF))[0] = ldu(scl, 0, isbf); return; }
    if (i == 75777)      { ((float*)(bias_base + SCLF))[1] = ldu(ab, 0, isbf); return; }
    if (i == 75778)      { ((float*)(bias_base + SCLF))[2] = ldu(wr1, 0, isbf); return; }
    if (i == 75779)      { ((float*)(bias_base + SCLF))[3] = ldu(wr2, 0, isbf); return; }
    return;
  }
  bid -= 297;
  const int tx = tid & 63, tg = tid >> 6;
  if (bid < 816) {                       // ---- transp_qkv ----
    int k0 = (bid % 17) * 64, z = bid / 17;
    int mode = z >> 4, h = z & 15;
    const void* src = (mode == 0) ? Wq : (mode == 1) ? Wk : Wv;
    const long soff = (long)h * 1025 * 64;
    int base_n = mode * 1024 + h * 64;
    for (int i = tg; i < 64; i += 4) {
      int k = k0 + i;
      tl[i][tx] = (k < 1025) ? ldu(src, soff + (long)k * 64 + tx, isbf) : 0.f;
    }
    __syncthreads();
    for (int i = tg; i < 64; i += 4) {
      int k = k0 + tx;
      if (k < LD_) wqkvT[(long)(base_n + i) * LD_ + k] = f2bf(tl[tx][i]);
    }
    return;
  }
  bid -= 816;
  if (bid < 272) {                       // ---- transp_wo (k-remap) ----
    int k0 = (bid % 17) * 64, n0 = (bid / 17) * 64;
    for (int i = tg; i < 64; i += 4) {
      int kp = k0 + i;
      float v = 0.f;
      if (kp < 1056) {
        int h = kp / 66, e = kp - h * 66;
        if (e < 65) v = ldu(Wo, (long)(h * 65 + e) * 1024 + n0 + tx, isbf);
      }
      tl[i][tx] = v;
    }
    __syncthreads();
    for (int i = tg; i < 64; i += 4) {
      int kp = k0 + tx;
      if (kp < LD_) woT[(long)(n0 + i) * LD_ + kp] = f2bf(tl[tx][i]);
    }
    return;
  }
  bid -= 272;
  if (bid < 1088) {                      // ---- W1^T: (1025,4096) -> (4096,LD_)
    int k0 = (bid % 17) * 64, n0 = (bid / 17) * 64;
    for (int i = tg; i < 64; i += 4) {
      int k = k0 + i;
      tl[i][tx] = (k < 1025) ? ldu(W1, (long)k * 4096 + n0 + tx, isbf) : 0.f;
    }
    __syncthreads();
    for (int i = tg; i < 64; i += 4) {
      int k = k0 + tx;
      if (k < LD_) w1T[(long)(n0 + i) * LD_ + k] = f2bf(tl[tx][i]);
    }
    return;
  }
  bid -= 1088;
  if (bid < 1024) {                      // ---- W2^T rows 1..4096: -> (1024,4096)
    int k0 = (bid % 64) * 64, n0 = (bid / 64) * 64;
    for (int i = tg; i < 64; i += 4) {
      int k = k0 + i;
      tl[i][tx] = ldu(W2, 1024 + (long)k * 1024 + n0 + tx, isbf);
    }
    __syncthreads();
    for (int i = tg; i < 64; i += 4) {
      int k = k0 + tx;
      w2T[(long)(n0 + i) * 4096 + k] = f2bf(tl[tx][i]);
    }
    return;
  }
  bid -= 1024;                           // ---- ln1: row = bid (0..4095) ----
  {
    float* red = &tl[0][0];
    const long base = (long)bid * 1025;
    const long obase = (long)bid * LD_;
    float v[4];
#pragma unroll
    for (int i = 0; i < 4; i++) v[i] = ldu(x, base + 1 + tid * 4 + i, isbf);
    float s = 0.f, s2 = 0.f;
#pragma unroll
    for (int i = 0; i < 4; i++) { s += v[i]; s2 += v[i] * v[i]; }
    s  = bred_f(s,  red);
    s2 = bred_f(s2, red);
    const float mu  = s * (1.f / 1024.f);
    const float var = s2 * (1.f / 1024.f) - mu * mu;
    const float rs  = rsqrtf(var + 1e-5f);
    float n[4], ns = 0.f;
#pragma unroll
    for (int i = 0; i < 4; i++) {
      const int e = tid * 4 + i;
      n[i] = (v[i] - mu) * rs * ldu(n1g, e, isbf) + ldu(n1b, e, isbf);
      ns += n[i] * n[i];
    }
    ns = bred_f(ns, red);
    if (tid == 0) xnb[obase] = f2bf(sqrtf(ns + 1.f));
#pragma unroll
    for (int i = 0; i < 4; i++) xnb[obase + 1 + tid * 4 + i] = f2bf(n[i]);
    if (tid < 63) xnb[obase + 1025 + tid] = f2bf(0.f);
  }
}

// ======================= 256x256 4-phase GEMM engine =====================
// 512 threads = 8 waves (2M x 4N). BK=64 (128B rows), dbuf=2 for A and B.
// BUFS = 16384 SHORTS per buffer (256 rows x 64 bf16 = 32 KiB).
// ROUND-12: deep prefetch. Both A(t+2) and B(t+2) staged during tile t
// (B: P3/P4, A: P4). Tile-end wait is vmcnt(8): never waits on loads
// issued this tile, only forces {A(t+1),B(t+1)} (issued a full tile
// earlier) landed. Hazards: staging overwrites current-tile buffers, so
// block-wide read completion is enforced by LGKM_GUARD before P2-trailing
// barrier (covers af03/b01/b23 -> B staging in P3/P4) and before
// P3-trailing barrier (covers af47 -> A staging in P4).
#define BUFS 16384
__device__ __forceinline__ void g256_main(const bf16* __restrict__ A, int lda,
                                          const bf16* __restrict__ Bw, int ldb, int K,
                                          int m0, int n0,
                                          short* __restrict__ AsB, short* __restrict__ BsB,
                                          f32x4 (*acc)[4]) {
  const int tid = threadIdx.x, lane = tid & 63, wv = tid >> 6;
  const int quad = lane >> 4, q15 = lane & 15;
  const int wm = wv >> 2, wn = wv & 3;
  const int NT = K >> 6;
  // staging: inst j covers rows j*64 + (tid>>3); 8 lanes/row, full 128B row.
  // LDS 16B-unit (row*8 + li) holds global unit (li ^ (row&7)).
  const int srow = tid >> 3;
  const int sunit = (tid & 7) ^ (srow & 7);
  const bf16* pa[4]; const bf16* pb[4];
#pragma unroll
  for (int j = 0; j < 4; j++) {
    pa[j] = A  + (long)(m0 + j * 64 + srow) * lda + sunit * 8;
    pb[j] = Bw + (long)(n0 + j * 64 + srow) * ldb + sunit * 8;
  }
  // prologue: A(0),B(0) -> buf0; A(1),B(1) -> buf1; pa/pb end at tile 2.
#pragma unroll
  for (int j = 0; j < 4; j++) gload16(pa[j], AsB + (j * 512 + tid) * 8);
#pragma unroll
  for (int j = 0; j < 4; j++) gload16(pb[j], BsB + (j * 512 + tid) * 8);
#pragma unroll
  for (int j = 0; j < 4; j++) { pa[j] += 64; pb[j] += 64; }
#pragma unroll
  for (int j = 0; j < 4; j++) gload16(pa[j], AsB + BUFS + (j * 512 + tid) * 8);
#pragma unroll
  for (int j = 0; j < 4; j++) gload16(pb[j], BsB + BUFS + (j * 512 + tid) * 8);
#pragma unroll
  for (int j = 0; j < 4; j++) { pa[j] += 64; pb[j] += 64; }
  // tile-0 buffers resident; tile-1's 8 loads may remain in flight.
  asm volatile("s_waitcnt vmcnt(8)" ::: "memory");
  __builtin_amdgcn_s_barrier();
  // read addressing (shorts): row*64 + ((unit)^(row&7))*8, row%8 == q15%8
  const int aoff = wm * 128 * 64 + q15 * 64;
  const int boff = wn * 64 * 64 + q15 * 64;
  const int rd0 = ((quad) ^ (q15 & 7)) * 8;
  const int rd1 = ((4 + quad) ^ (q15 & 7)) * 8;
#pragma unroll 1
  for (int t = 0; t < NT; t++) {
    const int c = t & 1;
    const short* Ab = AsB + c * BUFS;
    const short* Bb = BsB + c * BUFS;
    short* Ast = AsB + c * BUFS;         // A(t+2) overwrites A(t)'s buffer
    short* Bst = BsB + c * BUFS;         // B(t+2) overwrites B(t)'s buffer
    short8 af[4][2], b01[2][2], b23[2][2];
    // ---- P1: read af03 (8) + bf01 (4); no staging (deep prefetch in P4)
#pragma unroll
    for (int f = 0; f < 4; f++) {
      af[f][0] = *(const short8*)(Ab + aoff + f * 16 * 64 + rd0);
      af[f][1] = *(const short8*)(Ab + aoff + f * 16 * 64 + rd1);
    }
#pragma unroll
    for (int g = 0; g < 2; g++) {
      b01[g][0] = *(const short8*)(Bb + boff + g * 16 * 64 + rd0);
      b01[g][1] = *(const short8*)(Bb + boff + g * 16 * 64 + rd1);
    }
    DS_PIN();
    __builtin_amdgcn_s_barrier();
    __builtin_amdgcn_s_setprio(1);
#pragma unroll
    for (int kk = 0; kk < 2; kk++)
#pragma unroll
      for (int f = 0; f < 4; f++)
#pragma unroll
        for (int g = 0; g < 2; g++)
          MFMA_(acc[f][g], af[f][kk], b01[g][kk]);
    __builtin_amdgcn_s_setprio(0);
    __builtin_amdgcn_s_barrier();
    // ---- P2: read bf23 (4); MFMA af03 x bf23
#pragma unroll
    for (int g = 0; g < 2; g++) {
      b23[g][0] = *(const short8*)(Bb + boff + (32 + g * 16) * 64 + rd0);
      b23[g][1] = *(const short8*)(Bb + boff + (32 + g * 16) * 64 + rd1);
    }
    DS_PIN();
    __builtin_amdgcn_s_barrier();
    __builtin_amdgcn_s_setprio(1);
#pragma unroll
    for (int kk = 0; kk < 2; kk++)
#pragma unroll
      for (int f = 0; f < 4; f++)
#pragma unroll
        for (int g = 0; g < 2; g++)
          MFMA_(acc[f][2 + g], af[f][kk], b23[g][kk]);
    __builtin_amdgcn_s_setprio(0);
    LGKM_GUARD();     // af03/b01/b23 reads complete before B staging (P3/P4)
    __builtin_amdgcn_s_barrier();
    // ---- P3: read af47 (8); stage B-half0(t+2); MFMA af47 x bf01
#pragma unroll
    for (int f = 0; f < 4; f++) {
      af[f][0] = *(const short8*)(Ab + aoff + (64 + f * 16) * 64 + rd0);
      af[f][1] = *(const short8*)(Ab + aoff + (64 + f * 16) * 64 + rd1);
    }
    if (t + 2 < NT) {
      gload16(pb[0], Bst + (0 * 512 + tid) * 8);
      gload16(pb[1], Bst + (1 * 512 + tid) * 8);
    }
    DS_PIN();
    __builtin_amdgcn_s_barrier();
    __builtin_amdgcn_s_setprio(1);
#pragma unroll
    for (int kk = 0; kk < 2; kk++)
#pragma unroll
      for (int f = 0; f < 4; f++)
#pragma unroll
        for (int g = 0; g < 2; g++)
          MFMA_(acc[4 + f][g], af[f][kk], b01[g][kk]);
    __builtin_amdgcn_s_setprio(0);
    LGKM_GUARD();     // af47 reads complete before A staging (P4)
    __builtin_amdgcn_s_barrier();
    // ---- P4: stage B-half1(t+2) + A(t+2); MFMA af47 x bf23; vmcnt(8)
    if (t + 2 < NT) {
      gload16(pb[2], Bst + (2 * 512 + tid) * 8);
      gload16(pb[3], Bst + (3 * 512 + tid) * 8);
#pragma unroll
      for (int j = 0; j < 4; j++) gload16(pa[j], Ast + (j * 512 + tid) * 8);
#pragma unroll
      for (int j = 0; j < 4; j++) { pa[j] += 64; pb[j] += 64; }
    }
    __builtin_amdgcn_s_setprio(1);
#pragma unroll
    for (int kk = 0; kk < 2; kk++)
#pragma unroll
      for (int f = 0; f < 4; f++)
#pragma unroll
        for (int g = 0; g < 2; g++)
          MFMA_(acc[4 + f][2 + g], af[f][kk], b23[g][kk]);
    __builtin_amdgcn_s_setprio(0);
    // vmcnt(8): keep this tile's 8 staged loads in flight; force all older
    // ({A(t+1),B(t+1)}) landed -- exactly what tile t+1 reads. Tail drains.
    if (t + 2 < NT) {
      asm volatile("s_waitcnt vmcnt(8) lgkmcnt(0)" ::: "memory");
    } else {
      asm volatile("s_waitcnt vmcnt(0) lgkmcnt(0)" ::: "memory");
    }
    __builtin_amdgcn_s_barrier();
  }
}

// acc row offset for acc index j: j*16 (+ quad*4 + r)
template <int EPI>
__global__ __launch_bounds__(512) void gemm256(const bf16* __restrict__ A, int lda,
                                               const bf16* __restrict__ Bw, int ldb, int K,
                                               const float* __restrict__ bias,
                                               void* __restrict__ Cv, int ldc, int accf) {
  __shared__ __align__(16) short As[2][BUFS];
  __shared__ __align__(16) short Bs[2][BUFS];
  f32x4 acc[8][4] = {};
  const int m0 = blockIdx.y * 256, n0 = blockIdx.x * 256;
  g256_main(A, lda, Bw, ldb, K, m0, n0, &As[0][0], &Bs[0][0], acc);
  const int tid = threadIdx.x, lane = tid & 63, wv = tid >> 6;
  const int quad = lane >> 4, q15 = lane & 15;
  const int wave_m = wv >> 2, wave_n = wv & 3;
#pragma unroll
  for (int j = 0; j < 8; j++) {
#pragma unroll
    for (int r = 0; r < 4; r++) {
      const int m = m0 + wave_m * 128 + j * 16 + quad * 4 + r;
#pragma unroll
      for (int ni = 0; ni < 4; ni++) {
        const int n = n0 + wave_n * 64 + ni * 16 + q15;
        float v = acc[j][ni][r] + (bias ? bias[n] : 0.f);
        const long idx = (long)m * ldc + n;
        if (EPI == 0) {
          float* Cf = (float*)Cv;
          if (accf) v += Cf[idx];
          Cf[idx] = v;
        } else if (EPI == 1) {
          ((bf16*)Cv)[idx] = f2bf(v);
        } else {
          ((bf16*)Cv)[idx] = f2bf(gelu_f(v));
        }
      }
    }
  }
}

// ---- fused QKV GEMM on the 256x256 pipeline + rope/norm/manifold epilogue
// wave_n covers exactly one 64-col head-group: hg = blockIdx.x*4 + wave_n
__global__ __launch_bounds__(512) void gemm_qkv256(const bf16* __restrict__ A,
                                                   const bf16* __restrict__ Wt,
                                                   const char* __restrict__ bias_base,
                                                   bf16* __restrict__ qPs, float* __restrict__ qtc,
                                                   bf16* __restrict__ kPs, float* __restrict__ ktc,
                                                   bf16* __restrict__ vT) {
  __shared__ __align__(16) short As[2][BUFS];
  __shared__ __align__(16) short Bs[2][BUFS];
  f32x4 acc[8][4] = {};
  const int m0 = blockIdx.y * 256, n0 = blockIdx.x * 256;
  g256_main(A, LD_, Wt, LD_, LD_, m0, n0, &As[0][0], &Bs[0][0], acc);
  const int tid = threadIdx.x, lane = tid & 63, wv = tid >> 6;
  const int quad = lane >> 4, q15 = lane & 15;
  const int wave_m = wv >> 2, wave_n = wv & 3;
  const float* bqkvf = (const float*)(bias_base + BQKV);
  const float* rcf   = (const float*)(bias_base + RCF);
  const float* rsnf  = (const float*)(bias_base + RSNF);
  const int hg = (n0 >> 6) + wave_n;   // 0..47
  const int mode = hg >> 4, h = hg & 15;
  const int nb = hg * 64;
#pragma unroll
  for (int j = 0; j < 8; j++) {
#pragma unroll
    for (int r = 0; r < 4; r++) {
      const int m = m0 + wave_m * 128 + j * 16 + quad * 4 + r;
      const int bb = m >> 10, s = m & 1023;
      const int bh = bb * H_ + h;
      float v[4];
#pragma unroll
      for (int ns = 0; ns < 4; ns++) v[ns] = acc[j][ns][r] + bqkvf[nb + ns * 16 + q15];
      if (mode < 2) {
#pragma unroll
        for (int ns = 0; ns < 4; ns++) {
          const int eg = ns * 16 + q15;
          const int jj = eg >> 1;
          const float c = rcf[s * 32 + jj], sn = rsnf[s * 32 + jj];
          const float p = __shfl_xor(v[ns], 1);
          v[ns] = ((eg & 1) == 0) ? (v[ns] * c - p * sn) : (p * sn + v[ns] * c);
        }
      }
      float ss = v[0] * v[0] + v[1] * v[1] + v[2] * v[2] + v[3] * v[3];
#pragma unroll
      for (int o = 8; o; o >>= 1) ss += __shfl_xor(ss, o);
      if (mode == 0) {
        const float sc = rsqrtf(ss + 1e-6f);
        const long rb2 = (long)(bh * 1024 + s) * 64;
#pragma unroll
        for (int ns = 0; ns < 4; ns++) qPs[rb2 + ns * 16 + q15] = f2bf(v[ns] * sc);
        if (q15 == 0) qtc[bh * 1024 + s] = sqrtf(ss / (ss + 1e-6f) + 1.f);
      } else if (mode == 1) {
        const float sc = rsqrtf(ss + 1e-6f);
        const long rb2 = (long)(bh * 1024 + s) * 64;
#pragma unroll
        for (int ns = 0; ns < 4; ns++) kPs[rb2 + ns * 16 + q15] = f2bf(v[ns] * sc);
        if (q15 == 0) ktc[bh * 1024 + s] = sqrtf(ss / (ss + 1e-6f) + 1.f);
      } else {
        const long vb = (long)bh * 81920;
#pragma unroll
        for (int ns = 0; ns < 4; ns++) vT[vb + (long)(1 + ns * 16 + q15) * 1024 + s] = f2bf(v[ns]);
        if (q15 == 0) vT[vb + s] = f2bf(sqrtf(ss + 1.f));
      }
    }
  }
}

// ---------------- 128Mx64N MFMA GEMM, BK=64 -----------------------------
// K mult of 64. EPI: 0 = f32 out (+= if accf), 1 = bf16 out, 2 = gelu bf16
// XCD-swizzled blocks (T1). Split-K via blockIdx.z: K-offset = z*kz elems;
// z=1 writes EPI0 output to Cz1 instead of Cv (no atomics, no races).
template <int EPI, bool SS>
__global__ __launch_bounds__(256) void mfma_gemm(const bf16* __restrict__ A, int lda,
                                                 const bf16* __restrict__ Bw, int ldb, int K,
                                                 const float* __restrict__ bias,
                                                 void* __restrict__ Cv, int ldc, int accf,
                                                 float* __restrict__ tacc,
                                                 int kz, float* __restrict__ Cz1) {
  __shared__ __align__(16) short As[2][128 * 32];
  __shared__ __align__(16) short Bs[2][64 * 32];
  const int tid = threadIdx.x, lane = tid & 63, wv = tid >> 6;
  const int quad = lane >> 4, q15 = lane & 15;
  const int wave_m = wv & 1, wave_n = wv >> 1;
  int bx, by;
  xcd_swz(bx, by);
  const int n0 = bx * 64, m0 = by * 128;
  const long zoff = (long)blockIdx.z * kz;
  const int sa0 = wv * 128 + lane, sa1 = sa0 + 64;
  const int ra0 = sa0 >> 2, ca0 = (sa0 & 3) ^ (ra0 & 3);
  const int ra1 = sa1 >> 2, ca1 = (sa1 & 3) ^ (ra1 & 3);
  const int rb = tid >> 2, cb = (tid & 3) ^ (rb & 3);
  const int kswz = (quad ^ (q15 & 3)) * 8;
  const bf16* pa0 = A + zoff + (long)(m0 + ra0) * lda + ca0 * 8;
  const bf16* pa1 = A + zoff + (long)(m0 + ra1) * lda + ca1 * 8;
  const bf16* pb  = Bw + zoff + (long)(n0 + rb) * ldb + cb * 8;
  f32x4 acc[4][2] = {};
  for (int k0 = 0; k0 < K; k0 += 64) {
#pragma unroll
    for (int p = 0; p < 2; p++) {
      gload16(pa0 + p * 32, As[p] + sa0 * 8);
      gload16(pa1 + p * 32, As[p] + sa1 * 8);
      gload16(pb + p * 32, Bs[p] + tid * 8);
    }
    pa0 += 64; pa1 += 64; pb += 64;
    __syncthreads();
#pragma unroll
    for (int p = 0; p < 2; p++) {
      short8 af[4], bfr[2];
#pragma unroll
      for (int i = 0; i < 4; i++)
        af[i] = *(const short8*)(As[p] + (wave_m * 64 + i * 16 + q15) * 32 + kswz);
#pragma unroll
      for (int i = 0; i < 2; i++)
        bfr[i] = *(const short8*)(Bs[p] + (wave_n * 32 + i * 16 + q15) * 32 + kswz);
#pragma unroll
      for (int mi = 0; mi < 4; mi++)
#pragma unroll
        for (int ni = 0; ni < 2; ni++)
          acc[mi][ni] = __builtin_amdgcn_mfma_f32_16x16x32_bf16(af[mi], bfr[ni], acc[mi][ni], 0, 0, 0);
    }
    __syncthreads();
  }
#pragma unroll
  for (int mi = 0; mi < 4; mi++) {
#pragma unroll
    for (int r = 0; r < 4; r++) {
      const int m = m0 + wave_m * 64 + mi * 16 + quad * 4 + r;
      float s2 = 0.f;
#pragma unroll
      for (int ni = 0; ni < 2; ni++) {
        const int n = n0 + wave_n * 32 + ni * 16 + q15;
        float v = acc[mi][ni][r] + (bias ? bias[n] : 0.f);
        const long idx = (long)m * ldc + n;
        if (EPI == 0) {
          float* Cf = (blockIdx.z && Cz1) ? Cz1 : (float*)Cv;
          if (accf) v += Cf[idx];
          Cf[idx] = v;
        } else if (EPI == 1) {
          ((bf16*)Cv)[idx] = f2bf(v);
        } else {
          v = gelu_f(v);
          ((bf16*)Cv)[idx] = f2bf(v);
        }
        if (SS) s2 += v * v;
      }
      if (SS) {
        s2 += __shfl_xor(s2, 1);
        s2 += __shfl_xor(s2, 2);
        s2 += __shfl_xor(s2, 4);
        s2 += __shfl_xor(s2, 8);
        if (q15 == 0) atomicAdd(tacc + m, s2);
      }
    }
  }
}

// ---------------- MFMA flash attention (static max, XCD swizzle) --------
// mcat layout: (R, LD_), head h at cols [h*66, h*66+65], pads zeroed
__global__ __launch_bounds__(256) void attn_kernel(const bf16* __restrict__ qPs,
                                                   const float* __restrict__ qtc,
                                                   const bf16* __restrict__ kPs,
                                                   const float* __restrict__ ktc,
                                                   const bf16* __restrict__ vT,
                                                   const float* __restrict__ scalf,
                                                   bf16* __restrict__ mcat) {
  __shared__ __align__(16) short kbuf[64 * 72];
  __shared__ __align__(16) short vbuf[80 * 72];
  __shared__ __align__(16) short pbuf[64 * 72];
  __shared__ float tkl[64];
  const int tid = threadIdx.x, lane = tid & 63, wv = tid >> 6;
  const int quad = lane >> 4, q15 = lane & 15;
  const int id = blockIdx.x;
  const int cxd = id & 7, jj_ = id >> 3;
  const int bh = cxd * 8 + (jj_ & 7), qt_ = jj_ >> 3;
  const float inv_scale = 1.f / scalf[0];
  const long qrow = (long)(bh * 1024 + qt_ * 64 + wv * 16 + q15) * 64;
  const short8 aq0 = *(const short8*)(qPs + qrow + quad * 8);
  const short8 aq1 = *(const short8*)(qPs + qrow + 32 + quad * 8);
  float tqr[4];
#pragma unroll
  for (int r = 0; r < 4; r++) tqr[r] = qtc[bh * 1024 + qt_ * 64 + wv * 16 + quad * 4 + r];
  f32x4 out[5];
#pragma unroll
  for (int mt = 0; mt < 5; mt++) out[mt] = f32x4{0, 0, 0, 0};
  float lip[4] = {0.f, 0.f, 0.f, 0.f};
  const int srcl = (q15 >> 2) << 4;
  for (int kt = 0; kt < 16; kt++) {
    __syncthreads();
#pragma unroll
    for (int c = 0; c < 2; c++) {
      const int id2 = c * 256 + tid, row = id2 >> 3, off = id2 & 7;
      *(uint4*)(kbuf + row * 72 + off * 8) =
          *(const uint4*)(kPs + (long)(bh * 1024 + kt * 64 + row) * 64 + off * 8);
    }
#pragma unroll
    for (int c = 0; c < 3; c++) {
      const int id2 = c * 256 + tid;
      if (id2 < 640) {
        const int row = id2 >> 3, off = id2 & 7;
        *(uint4*)(vbuf + row * 72 + off * 8) =
            *(const uint4*)(vT + (long)bh * 81920 + (long)row * 1024 + kt * 64 + off * 8);
      }
    }
    if (tid < 64) tkl[tid] = ktc[bh * 1024 + kt * 64 + tid];
    __syncthreads();
    f32x4 sacc[4] = {f32x4{0,0,0,0}, f32x4{0,0,0,0}, f32x4{0,0,0,0}, f32x4{0,0,0,0}};
#pragma unroll
    for (int ns = 0; ns < 4; ns++) {
      short8 b0 = *(const short8*)(kbuf + (ns * 16 + q15) * 72 + quad * 8);
      short8 b1 = *(const short8*)(kbuf + (ns * 16 + q15) * 72 + 32 + quad * 8);
      sacc[ns] = __builtin_amdgcn_mfma_f32_16x16x32_bf16(aq0, b0, sacc[ns], 0, 0, 0);
      sacc[ns] = __builtin_amdgcn_mfma_f32_16x16x32_bf16(aq1, b1, sacc[ns], 0, 0, 0);
    }
#pragma unroll
    for (int ns = 0; ns < 4; ns++) {
      const float tk = tkl[ns * 16 + q15];
#pragma unroll
      for (int r = 0; r < 4; r++) {
        const float pv = __expf((2.f + 2.f * (sacc[ns][r] - tqr[r] * tk)) * inv_scale);
        lip[r] += pv;
        pbuf[(wv * 16 + quad * 4 + r) * 72 + ns * 16 + q15] = (short)bf2s(pv);
      }
    }
#pragma unroll
    for (int mt = 0; mt < 5; mt++)
#pragma unroll
      for (int kc = 0; kc < 2; kc++) {
        short8 av = *(const short8*)(vbuf + (mt * 16 + q15) * 72 + kc * 32 + quad * 8);
        short8 bp = *(const short8*)(pbuf + (wv * 16 + q15) * 72 + kc * 32 + quad * 8);
        out[mt] = __builtin_amdgcn_mfma_f32_16x16x32_bf16(av, bp, out[mt], 0, 0, 0);
      }
  }
  {
#pragma unroll
    for (int o = 8; o; o >>= 1)
#pragma unroll
      for (int r = 0; r < 4; r++) lip[r] += __shfl_xor(lip[r], o);
    float linv[4];
#pragma unroll
    for (int r = 0; r < 4; r++) linv[r] = 1.f / lip[r];
    const float t0 = __shfl(linv[0], srcl), t1 = __shfl(linv[1], srcl);
    const float t2 = __shfl(linv[2], srcl), t3 = __shfl(linv[3], srcl);
    const int rr = q15 & 3;
    const float lv = (rr == 0) ? t0 : (rr == 1) ? t1 : (rr == 2) ? t2 : t3;
#pragma unroll
    for (int mt = 0; mt < 5; mt++)
#pragma unroll
      for (int j = 0; j < 4; j++) out[mt][j] *= lv;
  }
  float part = 0.f;
#pragma unroll
  for (int mt = 0; mt < 5; mt++)
#pragma unroll
    for (int j = 0; j < 4; j++) {
      const int e = mt * 16 + quad * 4 + j;
      const float vv = out[mt][j] * out[mt][j];
      part += (e == 0) ? vv : -vv;
    }
  part += __shfl_xor(part, 16);
  part += __shfl_xor(part, 32);
  const float dinv = rsqrtf(fmaxf(part, 1e-6f));
  __syncthreads();
  short* obuf = vbuf;
  const int qrow_l = wv * 16 + q15;
#pragma unroll
  for (int mt = 0; mt < 5; mt++)
#pragma unroll
    for (int j = 0; j < 4; j++) {
      const int e = mt * 16 + quad * 4 + j;
      if (e <= 64) obuf[qrow_l * 72 + e] = (short)bf2s(out[mt][j] * dinv);
    }
  if (quad == 1) obuf[qrow_l * 72 + 65] = 0;
  __syncthreads();
  const int b = bh >> 4, h = bh & 15;
  const long outbase = ((long)b * 1024 + qt_ * 64) * LD_ + h * 66;
  for (int i = tid; i < 64 * 33; i += 256) {
    const int row = i / 33, p = i - row * 33;
    *(unsigned*)(mcat + outbase + (long)row * LD_ + p * 2) =
        *(const unsigned*)(obuf + row * 72 + p * 2);
  }
  if (h == 15) {
    const long zb = ((long)b * 1024 + qt_ * 64) * LD_ + 1056;
    for (int i = tid; i < 64 * 16; i += 256) {
      const int row = i >> 4, p = i & 15;
      *(unsigned*)(mcat + zb + (long)row * LD_ + p * 2) = 0u;
    }
  }
}

// ---------------- FF tail ------------------------------------------------
__global__ __launch_bounds__(256) void final_fix_kernel(const float* __restrict__ t_acc,
                                                        const float* __restrict__ w2r0,
                                                        const float* __restrict__ b2f,
                                                        float* __restrict__ mlp) {
  const int m = blockIdx.x;
  const float t = sqrtf(1.f + t_acc[m]);
  float* row = mlp + (long)m * 1024;
  for (int n = threadIdx.x; n < 1024; n += 256) row[n] += t * w2r0[n] + b2f[n];
}

// big path: also folds in the split-K z=1 partial (part1)
__global__ __launch_bounds__(256) void final_fix_big(const bf16* __restrict__ hh,
                                                     const float* __restrict__ w2r0,
                                                     const float* __restrict__ b2f,
                                                     const float* __restrict__ part1,
                                                     float* __restrict__ mlp) {
  __shared__ float red[4];
  const int m = blockIdx.x;
  const uint4* r4 = (const uint4*)(hh + (long)m * 4096);
  float ss = 0.f;
  for (int i = threadIdx.x; i < 512; i += 256) {
    const uint4 u = r4[i];
    const unsigned a[4] = {u.x, u.y, u.z, u.w};
#pragma unroll
    for (int j = 0; j < 4; j++) {
      const float lo = bfu_lo(a[j]), hi = bfu_hi(a[j]);
      ss += lo * lo + hi * hi;
    }
  }
  ss = bred_f(ss, red);
  const float t = sqrtf(1.f + ss);
  float* row = mlp + (long)m * 1024;
  const float* prow = part1 + (long)m * 1024;
  for (int n = threadIdx.x; n < 1024; n += 256)
    row[n] += prow[n] + t * w2r0[n] + b2f[n];
}

// ---------------- fused residual+project+layernorm (proj1 + ln2) ---------
// x2 = project(x + w*to_manifold(araw));  hbuf = hyp_layernorm(x2) (padded)
__global__ __launch_bounds__(256) void proj_ln_kernel(
    const void* __restrict__ x, const bf16* __restrict__ c,
    const float* __restrict__ scalf, int widx,
    const void* __restrict__ g, const void* __restrict__ b,
    bf16* __restrict__ x2, bf16* __restrict__ hbuf, const int* __restrict__ flag) {
  const int isbf = flag[0];
  __shared__ double redd[4];
  __shared__ float redf[4];
  const long bx = (long)blockIdx.x * 1025;
  const long bc = (long)blockIdx.x * 1024;
  const long ob = (long)blockIdx.x * LD_;
  const int tid = threadIdx.x;
  const double w = (double)scalf[widx];
  const float x0 = ldu(x, bx, isbf);
  float xs[4], cv[4];
#pragma unroll
  for (int i = 0; i < 4; i++) {
    xs[i] = ldu(x, bx + 1 + tid * 4 + i, isbf);
    cv[i] = bf2f(c[bc + tid * 4 + i]);
  }
  double cc = 0.0, xx = 0.0, xc = 0.0, sx = 0.0, sc_ = 0.0;
#pragma unroll
  for (int i = 0; i < 4; i++) {
    cc += (double)cv[i] * cv[i];
    xx += (double)xs[i] * xs[i];
    xc += (double)xs[i] * cv[i];
    sx += (double)xs[i];
    sc_ += (double)cv[i];
  }
  cc = bred_d(cc, redd);
  xx = bred_d(xx, redd);
  xc = bred_d(xc, redd);
  sx = bred_d(sx, redd);
  sc_ = bred_d(sc_, redd);
  const double t   = sqrt(1.0 + cc);
  const double lxx = (double)x0 * x0 - xx;
  const double xm  = -(double)x0 * t + xc;
  double d2 = lxx + w * w - 2.0 * w * xm;
  if (d2 < 1e-6) d2 = 1e-6;
  const double dinv = 1.0 / sqrt(d2);
  // write x2 (bf16, ld 1025)
  if (tid == 0) x2[bx] = f2bf((float)(((double)x0 + w * t) * dinv));
  float z[4];
#pragma unroll
  for (int i = 0; i < 4; i++) {
    z[i] = (float)(((double)xs[i] + w * cv[i]) * dinv);
    x2[bx + 1 + tid * 4 + i] = f2bf(z[i]);
  }
  // LN stats from analytic sums: sum z = dinv*(sx + w*sc_); sum z^2 = dinv^2*(xx+2w*xc+w^2*cc)
  const float sumz  = (float)((sx + w * sc_) * dinv);
  const float sumsq = (float)((xx + 2.0 * w * xc + w * w * cc) * dinv * dinv);
  const float mu  = sumz * (1.f / 1024.f);
  const float var = sumsq * (1.f / 1024.f) - mu * mu;
  const float rs  = rsqrtf(var + 1e-5f);
  float n[4], ns = 0.f;
#pragma unroll
  for (int i = 0; i < 4; i++) {
    const int e = tid * 4 + i;
    n[i] = (z[i] - mu) * rs * ldu(g, e, isbf) + ldu(b, e, isbf);
    ns += n[i] * n[i];
  }
  ns = bred_f(ns, redf);
  if (tid == 0) hbuf[ob] = f2bf(sqrtf(ns + 1.f));
#pragma unroll
  for (int i = 0; i < 4; i++) hbuf[ob + 1 + tid * 4 + i] = f2bf(n[i]);
  if (tid < 63) hbuf[ob + 1025 + tid] = f2bf(0.f);
}

// ---------------- residual + project (stable identity, f64 dots) ---------
__global__ __launch_bounds__(256) void res_project_kernel(
    const void* __restrict__ x, int xtag, const void* __restrict__ c, int ctag,
    const float* __restrict__ scalf, int widx, void* __restrict__ out, int otag,
    const int* __restrict__ flag) {
  const int isbf = flag[0];
  const int xb = (xtag == 2) ? isbf : xtag;
  const int cb2 = (ctag == 2) ? isbf : ctag;
  const int ob = (otag == 2) ? isbf : otag;
  __shared__ double red[4];
  const long bx = (long)blockIdx.x * 1025;
  const long bc = (long)blockIdx.x * 1024;
  const int tid = threadIdx.x;
  const double w = (double)scalf[widx];
  const float x0 = ldu(x, bx, xb);
  float xs[4], cv[4];
#pragma unroll
  for (int i = 0; i < 4; i++) {
    xs[i] = ldu(x, bx + 1 + tid * 4 + i, xb);
    cv[i] = ldu(c, bc + tid * 4 + i, cb2);
  }
  double cc = 0.0, xx = 0.0, xc = 0.0;
#pragma unroll
  for (int i = 0; i < 4; i++) {
    cc += (double)cv[i] * cv[i];
    xx += (double)xs[i] * xs[i];
    xc += (double)xs[i] * cv[i];
  }
  cc = bred_d(cc, red);
  xx = bred_d(xx, red);
  xc = bred_d(xc, red);
  const double t   = sqrt(1.0 + cc);
  const double lxx = (double)x0 * x0 - xx;
  const double xm  = -(double)x0 * t + xc;
  double d2 = lxx + w * w - 2.0 * w * xm;
  if (d2 < 1e-6) d2 = 1e-6;
  const double dinv = 1.0 / sqrt(d2);
  if (tid == 0) stu(out, bx, (float)(((double)x0 + w * t) * dinv), ob);
#pragma unroll
  for (int i = 0; i < 4; i++)
    stu(out, bx + 1 + tid * 4 + i, (float)(((double)xs[i] + w * cv[i]) * dinv), ob);
}

extern "C" void kernel_launch(void* const* d_in, const int* in_sizes, int n_in,
                              void* d_out, int out_size, void* d_ws, size_t ws_size,
                              hipStream_t stream) {
  char* w = (char*)d_ws;
  char* bias_base = w + OFF_BIAS;
  int* flag = (int*)(bias_base + FLAG);
  float* tacc = (float*)(bias_base + TACC);
  const float* scalf = (const float*)(bias_base + SCLF);
  const bool big = ws_size >= (size_t)92 * MBL;
  char* mlp_off = big ? (w + OFF_MLPB) : (w + OFF_MLPF);

  detect_kernel<<<1, 64, 0, stream>>>((const unsigned*)d_in[3], flag);
  zero16_kernel<<<4, 256, 0, stream>>>((uint4*)tacc, 1024);

  // all prep (scalars + 4 weight transposes + ln1) in one dispatch
  mega_prep<<<7593, 256, 0, stream>>>(
      d_in[0], d_in[1], d_in[2], d_in[3], d_in[4], d_in[5], d_in[6], d_in[7], d_in[8],
      d_in[9], d_in[10], d_in[11], d_in[12], d_in[13], d_in[14], d_in[15], d_in[18],
      d_in[19], d_in[20], d_in[21], d_in[22], bias_base, (bf16*)(w + OFF_WQKVT),
      (bf16*)(w + OFF_WOT), (bf16*)(w + OFF_W1T), (bf16*)(w + OFF_W2T),
      (bf16*)(w + OFF_XNB), flag);

  // QKV on the 256x256 deep-pipelined GEMM (N=3072 -> 12 col-blocks)
  gemm_qkv256<<<dim3(12, 16), 512, 0, stream>>>(
      (const bf16*)(w + OFF_XNB), (const bf16*)(w + OFF_WQKVT), bias_base,
      (bf16*)(w + OFF_QPS), (float*)(w + OFF_QT), (bf16*)(w + OFF_KPS),
      (float*)(w + OFF_KT), (bf16*)(w + OFF_VT));
  attn_kernel<<<1024, 256, 0, stream>>>(
      (const bf16*)(w + OFF_QPS), (const float*)(w + OFF_QT), (const bf16*)(w + OFF_KPS),
      (const float*)(w + OFF_KT), (const bf16*)(w + OFF_VT), scalf, (bf16*)(w + OFF_MCAT));
  mfma_gemm<1, false><<<dim3(16, 32), 256, 0, stream>>>(
      (const bf16*)(w + OFF_MCAT), LD_, (const bf16*)(w + OFF_WOT), LD_, LD_,
      (const float*)(bias_base + BOF), w + OFF_ARAW, 1024, 0, nullptr, 0, nullptr);
  // fused proj1 + ln2
  proj_ln_kernel<<<R_, 256, 0, stream>>>(d_in[0], (const bf16*)(w + OFF_ARAW), scalf, 2,
                                         d_in[16], d_in[17], (bf16*)(w + OFF_X2),
                                         (bf16*)(w + OFF_HBUF), flag);
  if (big) {
    // W1 GEMM (4096x4096xK=1088) on the 256x256 pipeline: 256 blocks = 1/CU
    gemm256<2><<<dim3(16, 16), 512, 0, stream>>>(
        (const bf16*)(w + OFF_HBUF), LD_, (const bf16*)(w + OFF_W1T), LD_, LD_,
        (const float*)(bias_base + B1F), w + OFF_HHBIG, 4096, 0);
    // W2 (4096x1024xK=4096), split-K=2 via grid z: z=0 -> mlp, z=1 -> part1.
    // 1024 blocks = 4/CU (occupancy was the r7-measured limiter at 512).
    mfma_gemm<0, false><<<dim3(16, 32, 2), 256, 0, stream>>>(
        (const bf16*)(w + OFF_HHBIG), 4096, (const bf16*)(w + OFF_W2T), 4096, 2048,
        nullptr, mlp_off, 1024, 0, nullptr, 2048, (float*)(w + OFF_PART1));
    final_fix_big<<<R_, 256, 0, stream>>>((const bf16*)(w + OFF_HHBIG),
                                          (const float*)(bias_base + W2R0),
                                          (const float*)(bias_base + B2F),
                                          (const float*)(w + OFF_PART1),
                                          (float*)mlp_off);
  } else {
    for (int c = 0; c < 4; c++) {
      mfma_gemm<2, true><<<dim3(16, 32), 256, 0, stream>>>(
          (const bf16*)(w + OFF_HBUF), LD_, (const bf16*)(w + OFF_W1T) + (long)c * 1024 * LD_,
          LD_, LD_, (const float*)(bias_base + B1F) + c * 1024, w + OFF_HHC, 1024, 0, tacc,
          0, nullptr);
      mfma_gemm<0, false><<<dim3(16, 32), 256, 0, stream>>>(
          (const bf16*)(w + OFF_HHC), 1024, (const bf16*)(w + OFF_W2T) + c * 1024, 4096, 1024,
          nullptr, mlp_off, 1024, c > 0 ? 1 : 0, nullptr, 0, nullptr);
    }
    final_fix_kernel<<<R_, 256, 0, stream>>>(tacc, (const float*)(bias_base + W2R0),
                                             (const float*)(bias_base + B2F),
                                             (float*)mlp_off);
  }
  res_project_kernel<<<R_, 256, 0, stream>>>(w + OFF_X2, 1, mlp_off, 0, scalf, 3,
                                             d_out, 2, flag);
}

// Round 14
// 459.712 us; speedup vs baseline: 1.0249x; 1.0249x over previous
//
#include <hip/hip_runtime.h>
#include <hip/hip_bf16.h>

typedef __hip_bfloat16 bf16;
typedef __attribute__((ext_vector_type(8))) short short8;
typedef __attribute__((ext_vector_type(4))) float f32x4;

#define B_  4
#define S_  1024
#define H_  16
#define R_  4096
#define LD_ 1088   // padded K / row stride for 1056-wide operands (mult of 64)

#define MBL 1048576L
// ---- workspace byte offsets (big path peak = 92 MiB; fallback peak = 60 MiB)
#define OFF_WQKVT (0L)
#define OFF_WOT   (6684672L)
#define OFF_X2    (0L)
#define OFF_W1T   (9L*MBL)
#define OFF_W2T   (18L*MBL)
#define OFF_BIAS  (26L*MBL)
#define OFF_XNB   (27L*MBL + MBL/2)
#define OFF_MCAT  OFF_XNB
#define OFF_HBUF  OFF_XNB
#define OFF_PART1 OFF_XNB          // W2 split-K z=1 partial (f32, 16 MiB);
                                   // XNB/ARAW dead by the time W2 runs.
                                   // 27.5+16=43.5 MiB < OFF_HHBIG (44 MiB).
#define OFF_QPS   (36L*MBL)
#define OFF_ARAW  OFF_QPS
#define OFF_KPS   (44L*MBL)
#define OFF_VT    (52L*MBL)
#define OFF_QT    (62L*MBL)
#define OFF_KT    (62L*MBL + 262144L)
#define OFF_HHBIG (44L*MBL)
#define OFF_MLPB  (76L*MBL)
#define OFF_HHC   (36L*MBL)
#define OFF_MLPF  (44L*MBL)
// bias block internal offsets (bytes from OFF_BIAS)
#define BQKV 0
#define BOF  16384
#define B1F  32768
#define B2F  65536
#define W2R0 81920
#define RCF  98304
#define RSNF 262144
#define SCLF 409600
#define TACC 425984
#define FLAG 458752

__device__ __forceinline__ bf16  f2bf(float v) { return __float2bfloat16(v); }
__device__ __forceinline__ float bf2f(bf16 v)  { return __bfloat162float(v); }
__device__ __forceinline__ unsigned short bf2s(float v) {
  return __builtin_bit_cast(unsigned short, __float2bfloat16(v));
}
__device__ __forceinline__ float ldu(const void* p, long i, int isbf) {
  return isbf ? bf2f(((const bf16*)p)[i]) : ((const float*)p)[i];
}
__device__ __forceinline__ void stu(void* p, long i, float v, int isbf) {
  if (isbf) ((bf16*)p)[i] = f2bf(v);
  else      ((float*)p)[i] = v;
}
__device__ __forceinline__ float gelu_f(float v) {
  const float u = 0.7978845608028654f * (v + 0.044715f * v * v * v);
  const float e = __expf(fminf(2.f * u, 80.f));
  return 0.5f * v * (1.f + (e - 1.f) / (e + 1.f));
}
__device__ __forceinline__ float bfu_lo(unsigned u) {
  return __builtin_bit_cast(float, u << 16);
}
__device__ __forceinline__ float bfu_hi(unsigned u) {
  return __builtin_bit_cast(float, u & 0xFFFF0000u);
}

// async global->LDS, 16B per lane. lds addr must equal wave-uniform base + lane*16.
__device__ __forceinline__ void gload16(const bf16* g, short* l) {
  __builtin_amdgcn_global_load_lds(
      (const __attribute__((address_space(1))) unsigned int*)g,
      (__attribute__((address_space(3))) unsigned int*)l, 16, 0, 0);
}

#define MFMA_(acc_, a_, b_) acc_ = __builtin_amdgcn_mfma_f32_16x16x32_bf16(a_, b_, acc_, 0, 0, 0)
// Read-completion guard: all of this wave's LDS reads done + reads cannot be
// reordered past this point (memory clobber). Does NOT touch vmcnt.
#define LGKM_GUARD() asm volatile("s_waitcnt lgkmcnt(0)" ::: "memory")
// DS-issue pin (null effect measured r6; kept, harmless).
#define DS_PIN() __builtin_amdgcn_sched_barrier(0x7F)

// Bijective chunked XCD swizzle (T1). Applied ONLY to mfma_gemm (W2/Wo):
// r7 measured FETCH 135->49 MB there. Not applied on gemm256/gemm_qkv256 —
// their operands are L3-fit, where swizzle costs ~2% (m160).
__device__ __forceinline__ void xcd_swz(int& bx, int& by) {
  const int nbx = gridDim.x;
  const int nb = nbx * gridDim.y;
  if ((nb & 7) == 0) {
    const int hid = blockIdx.y * nbx + blockIdx.x;
    const int l = (hid & 7) * (nb >> 3) + (hid >> 3);
    bx = l % nbx;
    by = l / nbx;
  } else {
    bx = blockIdx.x;
    by = blockIdx.y;
  }
}

__global__ void detect_kernel(const unsigned* __restrict__ g, int* __restrict__ flag) {
  if (threadIdx.x == 0) flag[0] = (g[0] == 0x3F803F80u) ? 1 : 0;
}

__global__ __launch_bounds__(256) void zero16_kernel(uint4* __restrict__ p, int n16) {
  int i = blockIdx.x * 256 + threadIdx.x;
  if (i < n16) p[i] = uint4{0, 0, 0, 0};
}

// block = 256 threads (4 waves)
__device__ __forceinline__ float bred_f(float v, float* sh) {
#pragma unroll
  for (int o = 32; o; o >>= 1) v += __shfl_xor(v, o);
  __syncthreads();
  if ((threadIdx.x & 63) == 0) sh[threadIdx.x >> 6] = v;
  __syncthreads();
  return sh[0] + sh[1] + sh[2] + sh[3];
}
__device__ __forceinline__ double bred_d(double v, double* sh) {
#pragma unroll
  for (int o = 32; o; o >>= 1) v += __shfl_xor(v, o);
  __syncthreads();
  if ((threadIdx.x & 63) == 0) sh[threadIdx.x >> 6] = v;
  __syncthreads();
  return sh[0] + sh[1] + sh[2] + sh[3];
}

// ---------------- mega_prep: prep_misc + 4 transposes + ln1, one dispatch
// block ranges: [0,297) misc | [297,1113) qkvT | [1113,1385) woT |
//               [1385,2473) w1T | [2473,3497) w2T | [3497,7593) ln1
__global__ __launch_bounds__(256) void mega_prep(
    const void* x, const void* rc, const void* rsn, const void* n1g, const void* n1b,
    const void* Wq, const void* bq, const void* Wk, const void* bk,
    const void* Wv, const void* bv, const void* scl, const void* ab,
    const void* Wo, const void* bo, const void* wr1,
    const void* W1, const void* b1, const void* W2, const void* b2, const void* wr2,
    char* bias_base, bf16* __restrict__ wqkvT, bf16* __restrict__ woT,
    bf16* __restrict__ w1T, bf16* __restrict__ w2T, bf16* __restrict__ xnb,
    const int* __restrict__ flag) {
  const int isbf = flag[0];
  __shared__ float tl[64][65];
  const int tid = threadIdx.x;
  int bid = blockIdx.x;
  if (bid < 297) {                       // ---- prep_misc ----
    int i = bid * 256 + tid;
    float* bqkvf = (float*)(bias_base + BQKV);
    if (i < 1024)        { bqkvf[i] = ldu(bq, i, isbf); return; }
    if (i < 2048)        { bqkvf[i] = ldu(bk, i - 1024, isbf); return; }
    if (i < 3072)        { bqkvf[i] = ldu(bv, i - 2048, isbf); return; }
    if (i < 4096)        { ((float*)(bias_base + BOF))[i - 3072] = ldu(bo, i - 3072, isbf); return; }
    if (i < 8192)        { ((float*)(bias_base + B1F))[i - 4096] = ldu(b1, i - 4096, isbf); return; }
    if (i < 9216)        { ((float*)(bias_base + B2F))[i - 8192] = ldu(b2, i - 8192, isbf); return; }
    if (i < 10240)       { ((float*)(bias_base + W2R0))[i - 9216] = ldu(W2, i - 9216, isbf); return; }
    if (i < 10240+32768) { ((float*)(bias_base + RCF))[i - 10240] = ldu(rc, i - 10240, isbf); return; }
    if (i < 10240+65536) { ((float*)(bias_base + RSNF))[i - 43008] = ldu(rsn, i - 43008, isbf); return; }
    if (i == 75776)      { ((float*)(bias_base + SCLF))[0] = ldu(scl, 0, isbf); return; }
    if (i == 75777)      { ((float*)(bias_base + SCLF))[1] = ldu(ab, 0, isbf); return; }
    if (i == 75778)      { ((float*)(bias_base + SCLF))[2] = ldu(wr1, 0, isbf); return; }
    if (i == 75779)      { ((float*)(bias_base + SCLF))[3] = ldu(wr2, 0, isbf); return; }
    return;
  }
  bid -= 297;
  const int tx = tid & 63, tg = tid >> 6;
  if (bid < 816) {                       // ---- transp_qkv ----
    int k0 = (bid % 17) * 64, z = bid / 17;
    int mode = z >> 4, h = z & 15;
    const void* src = (mode == 0) ? Wq : (mode == 1) ? Wk : Wv;
    const long soff = (long)h * 1025 * 64;
    int base_n = mode * 1024 + h * 64;
    for (int i = tg; i < 64; i += 4) {
      int k = k0 + i;
      tl[i][tx] = (k < 1025) ? ldu(src, soff + (long)k * 64 + tx, isbf) : 0.f;
    }
    __syncthreads();
    for (int i = tg; i < 64; i += 4) {
      int k = k0 + tx;
      if (k < LD_) wqkvT[(long)(base_n + i) * LD_ + k] = f2bf(tl[tx][i]);
    }
    return;
  }
  bid -= 816;
  if (bid < 272) {                       // ---- transp_wo (k-remap) ----
    int k0 = (bid % 17) * 64, n0 = (bid / 17) * 64;
    for (int i = tg; i < 64; i += 4) {
      int kp = k0 + i;
      float v = 0.f;
      if (kp < 1056) {
        int h = kp / 66, e = kp - h * 66;
        if (e < 65) v = ldu(Wo, (long)(h * 65 + e) * 1024 + n0 + tx, isbf);
      }
      tl[i][tx] = v;
    }
    __syncthreads();
    for (int i = tg; i < 64; i += 4) {
      int kp = k0 + tx;
      if (kp < LD_) woT[(long)(n0 + i) * LD_ + kp] = f2bf(tl[tx][i]);
    }
    return;
  }
  bid -= 272;
  if (bid < 1088) {                      // ---- W1^T: (1025,4096) -> (4096,LD_)
    int k0 = (bid % 17) * 64, n0 = (bid / 17) * 64;
    for (int i = tg; i < 64; i += 4) {
      int k = k0 + i;
      tl[i][tx] = (k < 1025) ? ldu(W1, (long)k * 4096 + n0 + tx, isbf) : 0.f;
    }
    __syncthreads();
    for (int i = tg; i < 64; i += 4) {
      int k = k0 + tx;
      if (k < LD_) w1T[(long)(n0 + i) * LD_ + k] = f2bf(tl[tx][i]);
    }
    return;
  }
  bid -= 1088;
  if (bid < 1024) {                      // ---- W2^T rows 1..4096: -> (1024,4096)
    int k0 = (bid % 64) * 64, n0 = (bid / 64) * 64;
    for (int i = tg; i < 64; i += 4) {
      int k = k0 + i;
      tl[i][tx] = ldu(W2, 1024 + (long)k * 1024 + n0 + tx, isbf);
    }
    __syncthreads();
    for (int i = tg; i < 64; i += 4) {
      int k = k0 + tx;
      w2T[(long)(n0 + i) * 4096 + k] = f2bf(tl[tx][i]);
    }
    return;
  }
  bid -= 1024;                           // ---- ln1: row = bid (0..4095) ----
  {
    float* red = &tl[0][0];
    const long base = (long)bid * 1025;
    const long obase = (long)bid * LD_;
    float v[4];
#pragma unroll
    for (int i = 0; i < 4; i++) v[i] = ldu(x, base + 1 + tid * 4 + i, isbf);
    float s = 0.f, s2 = 0.f;
#pragma unroll
    for (int i = 0; i < 4; i++) { s += v[i]; s2 += v[i] * v[i]; }
    s  = bred_f(s,  red);
    s2 = bred_f(s2, red);
    const float mu  = s * (1.f / 1024.f);
    const float var = s2 * (1.f / 1024.f) - mu * mu;
    const float rs  = rsqrtf(var + 1e-5f);
    float n[4], ns = 0.f;
#pragma unroll
    for (int i = 0; i < 4; i++) {
      const int e = tid * 4 + i;
      n[i] = (v[i] - mu) * rs * ldu(n1g, e, isbf) + ldu(n1b, e, isbf);
      ns += n[i] * n[i];
    }
    ns = bred_f(ns, red);
    if (tid == 0) xnb[obase] = f2bf(sqrtf(ns + 1.f));
#pragma unroll
    for (int i = 0; i < 4; i++) xnb[obase + 1 + tid * 4 + i] = f2bf(n[i]);
    if (tid < 63) xnb[obase + 1025 + tid] = f2bf(0.f);
  }
}

// ======================= 256x256 4-phase GEMM engine =====================
// 512 threads = 8 waves (2M x 4N). BK=64 (128B rows), dbuf=2 for A and B.
// BUFS = 16384 SHORTS per buffer (256 rows x 64 bf16 = 32 KiB).
#define BUFS 16384
__device__ __forceinline__ void g256_main(const bf16* __restrict__ A, int lda,
                                          const bf16* __restrict__ Bw, int ldb, int K,
                                          int m0, int n0,
                                          short* __restrict__ AsB, short* __restrict__ BsB,
                                          f32x4 (*acc)[4]) {
  const int tid = threadIdx.x, lane = tid & 63, wv = tid >> 6;
  const int quad = lane >> 4, q15 = lane & 15;
  const int wm = wv >> 2, wn = wv & 3;
  const int NT = K >> 6;
  // staging: inst j covers rows j*64 + (tid>>3); 8 lanes/row, full 128B row.
  // LDS 16B-unit (row*8 + li) holds global unit (li ^ (row&7)).
  const int srow = tid >> 3;
  const int sunit = (tid & 7) ^ (srow & 7);
  const bf16* pa[4]; const bf16* pb[4];
#pragma unroll
  for (int j = 0; j < 4; j++) {
    pa[j] = A  + (long)(m0 + j * 64 + srow) * lda + sunit * 8;
    pb[j] = Bw + (long)(n0 + j * 64 + srow) * ldb + sunit * 8;
  }
  // prologue: A(0),B(0) -> buf0; B(1) -> buf1
#pragma unroll
  for (int j = 0; j < 4; j++) gload16(pa[j], AsB + (j * 512 + tid) * 8);
#pragma unroll
  for (int j = 0; j < 4; j++) gload16(pb[j], BsB + (j * 512 + tid) * 8);
#pragma unroll
  for (int j = 0; j < 4; j++) { pb[j] += 64; gload16(pb[j], BsB + BUFS + (j * 512 + tid) * 8); }
#pragma unroll
  for (int j = 0; j < 4; j++) { pa[j] += 64; pb[j] += 64; }
  asm volatile("s_waitcnt vmcnt(4)" ::: "memory");
  __builtin_amdgcn_s_barrier();
  // read addressing (shorts): row*64 + ((unit)^(row&7))*8, row%8 == q15%8
  const int aoff = wm * 128 * 64 + q15 * 64;
  const int boff = wn * 64 * 64 + q15 * 64;
  const int rd0 = ((quad) ^ (q15 & 7)) * 8;
  const int rd1 = ((4 + quad) ^ (q15 & 7)) * 8;
#pragma unroll 1
  for (int t = 0; t < NT; t++) {
    const int c = t & 1;
    const short* Ab = AsB + c * BUFS;
    const short* Bb = BsB + c * BUFS;
    short* Ast = AsB + (c ^ 1) * BUFS;   // A(t+1)
    short* Bst = BsB + c * BUFS;         // B(t+2)
    short8 af[4][2], b01[2][2], b23[2][2];
    // ---- P1: read af03 (8) + bf01 (4); stage A(t+1)
#pragma unroll
    for (int f = 0; f < 4; f++) {
      af[f][0] = *(const short8*)(Ab + aoff + f * 16 * 64 + rd0);
      af[f][1] = *(const short8*)(Ab + aoff + f * 16 * 64 + rd1);
    }
#pragma unroll
    for (int g = 0; g < 2; g++) {
      b01[g][0] = *(const short8*)(Bb + boff + g * 16 * 64 + rd0);
      b01[g][1] = *(const short8*)(Bb + boff + g * 16 * 64 + rd1);
    }
    if (t + 1 < NT) {
#pragma unroll
      for (int j = 0; j < 4; j++) gload16(pa[j], Ast + (j * 512 + tid) * 8);
#pragma unroll
      for (int j = 0; j < 4; j++) pa[j] += 64;
    }
    DS_PIN();
    __builtin_amdgcn_s_barrier();
    __builtin_amdgcn_s_setprio(1);
#pragma unroll
    for (int kk = 0; kk < 2; kk++)
#pragma unroll
      for (int f = 0; f < 4; f++)
#pragma unroll
        for (int g = 0; g < 2; g++)
          MFMA_(acc[f][g], af[f][kk], b01[g][kk]);
    __builtin_amdgcn_s_setprio(0);
    __builtin_amdgcn_s_barrier();
    // ---- P2: read bf23 (4); MFMA af03 x bf23
#pragma unroll
    for (int g = 0; g < 2; g++) {
      b23[g][0] = *(const short8*)(Bb + boff + (32 + g * 16) * 64 + rd0);
      b23[g][1] = *(const short8*)(Bb + boff + (32 + g * 16) * 64 + rd1);
    }
    DS_PIN();
    __builtin_amdgcn_s_barrier();
    __builtin_amdgcn_s_setprio(1);
#pragma unroll
    for (int kk = 0; kk < 2; kk++)
#pragma unroll
      for (int f = 0; f < 4; f++)
#pragma unroll
        for (int g = 0; g < 2; g++)
          MFMA_(acc[f][2 + g], af[f][kk], b23[g][kk]);
    __builtin_amdgcn_s_setprio(0);
    LGKM_GUARD();                        // B(t) reads complete before P3 staging
    __builtin_amdgcn_s_barrier();
    // ---- P3: read af47 (8); stage B-half0(t+2); MFMA af47 x bf01
#pragma unroll
    for (int f = 0; f < 4; f++) {
      af[f][0] = *(const short8*)(Ab + aoff + (64 + f * 16) * 64 + rd0);
      af[f][1] = *(const short8*)(Ab + aoff + (64 + f * 16) * 64 + rd1);
    }
    if (t + 2 < NT) {
      gload16(pb[0], Bst + (0 * 512 + tid) * 8);
      gload16(pb[1], Bst + (1 * 512 + tid) * 8);
    }
    DS_PIN();
    __builtin_amdgcn_s_barrier();
    __builtin_amdgcn_s_setprio(1);
#pragma unroll
    for (int kk = 0; kk < 2; kk++)
#pragma unroll
      for (int f = 0; f < 4; f++)
#pragma unroll
        for (int g = 0; g < 2; g++)
          MFMA_(acc[4 + f][g], af[f][kk], b01[g][kk]);
    __builtin_amdgcn_s_setprio(0);
    __builtin_amdgcn_s_barrier();
    // ---- P4: stage B-half1(t+2); MFMA af47 x bf23; counted wait; barrier
    if (t + 2 < NT) {
      gload16(pb[2], Bst + (2 * 512 + tid) * 8);
      gload16(pb[3], Bst + (3 * 512 + tid) * 8);
#pragma unroll
      for (int j = 0; j < 4; j++) pb[j] += 64;
    }
    __builtin_amdgcn_s_setprio(1);
#pragma unroll
    for (int kk = 0; kk < 2; kk++)
#pragma unroll
      for (int f = 0; f < 4; f++)
#pragma unroll
        for (int g = 0; g < 2; g++)
          MFMA_(acc[4 + f][2 + g], af[f][kk], b23[g][kk]);
    __builtin_amdgcn_s_setprio(0);
    // A(t) reads complete (lgkmcnt 0) before next-iter A staging; counted
    // vmcnt leaves only B(t+2)'s 4 loads in flight.
    if (t + 2 < NT) {
      asm volatile("s_waitcnt vmcnt(4) lgkmcnt(0)" ::: "memory");
    } else {
      asm volatile("s_waitcnt vmcnt(0) lgkmcnt(0)" ::: "memory");
    }
    __builtin_amdgcn_s_barrier();
  }
}

// acc row offset for acc index j: j*16 (+ quad*4 + r)
template <int EPI>
__global__ __launch_bounds__(512) void gemm256(const bf16* __restrict__ A, int lda,
                                               const bf16* __restrict__ Bw, int ldb, int K,
                                               const float* __restrict__ bias,
                                               void* __restrict__ Cv, int ldc, int accf) {
  __shared__ __align__(16) short As[2][BUFS];
  __shared__ __align__(16) short Bs[2][BUFS];
  f32x4 acc[8][4] = {};
  const int m0 = blockIdx.y * 256, n0 = blockIdx.x * 256;
  g256_main(A, lda, Bw, ldb, K, m0, n0, &As[0][0], &Bs[0][0], acc);
  const int tid = threadIdx.x, lane = tid & 63, wv = tid >> 6;
  const int quad = lane >> 4, q15 = lane & 15;
  const int wave_m = wv >> 2, wave_n = wv & 3;
#pragma unroll
  for (int j = 0; j < 8; j++) {
#pragma unroll
    for (int r = 0; r < 4; r++) {
      const int m = m0 + wave_m * 128 + j * 16 + quad * 4 + r;
#pragma unroll
      for (int ni = 0; ni < 4; ni++) {
        const int n = n0 + wave_n * 64 + ni * 16 + q15;
        float v = acc[j][ni][r] + (bias ? bias[n] : 0.f);
        const long idx = (long)m * ldc + n;
        if (EPI == 0) {
          float* Cf = (float*)Cv;
          if (accf) v += Cf[idx];
          Cf[idx] = v;
        } else if (EPI == 1) {
          ((bf16*)Cv)[idx] = f2bf(v);
        } else {
          ((bf16*)Cv)[idx] = f2bf(gelu_f(v));
        }
      }
    }
  }
}

// ---- fused QKV GEMM on the 256x256 pipeline + rope/norm/manifold epilogue
// wave_n covers exactly one 64-col head-group: hg = blockIdx.x*4 + wave_n
__global__ __launch_bounds__(512) void gemm_qkv256(const bf16* __restrict__ A,
                                                   const bf16* __restrict__ Wt,
                                                   const char* __restrict__ bias_base,
                                                   bf16* __restrict__ qPs, float* __restrict__ qtc,
                                                   bf16* __restrict__ kPs, float* __restrict__ ktc,
                                                   bf16* __restrict__ vT) {
  __shared__ __align__(16) short As[2][BUFS];
  __shared__ __align__(16) short Bs[2][BUFS];
  f32x4 acc[8][4] = {};
  const int m0 = blockIdx.y * 256, n0 = blockIdx.x * 256;
  g256_main(A, LD_, Wt, LD_, LD_, m0, n0, &As[0][0], &Bs[0][0], acc);
  const int tid = threadIdx.x, lane = tid & 63, wv = tid >> 6;
  const int quad = lane >> 4, q15 = lane & 15;
  const int wave_m = wv >> 2, wave_n = wv & 3;
  const float* bqkvf = (const float*)(bias_base + BQKV);
  const float* rcf   = (const float*)(bias_base + RCF);
  const float* rsnf  = (const float*)(bias_base + RSNF);
  const int hg = (n0 >> 6) + wave_n;   // 0..47
  const int mode = hg >> 4, h = hg & 15;
  const int nb = hg * 64;
#pragma unroll
  for (int j = 0; j < 8; j++) {
#pragma unroll
    for (int r = 0; r < 4; r++) {
      const int m = m0 + wave_m * 128 + j * 16 + quad * 4 + r;
      const int bb = m >> 10, s = m & 1023;
      const int bh = bb * H_ + h;
      float v[4];
#pragma unroll
      for (int ns = 0; ns < 4; ns++) v[ns] = acc[j][ns][r] + bqkvf[nb + ns * 16 + q15];
      if (mode < 2) {
#pragma unroll
        for (int ns = 0; ns < 4; ns++) {
          const int eg = ns * 16 + q15;
          const int jj = eg >> 1;
          const float c = rcf[s * 32 + jj], sn = rsnf[s * 32 + jj];
          const float p = __shfl_xor(v[ns], 1);
          v[ns] = ((eg & 1) == 0) ? (v[ns] * c - p * sn) : (p * sn + v[ns] * c);
        }
      }
      float ss = v[0] * v[0] + v[1] * v[1] + v[2] * v[2] + v[3] * v[3];
#pragma unroll
      for (int o = 8; o; o >>= 1) ss += __shfl_xor(ss, o);
      if (mode == 0) {
        const float sc = rsqrtf(ss + 1e-6f);
        const long rb2 = (long)(bh * 1024 + s) * 64;
#pragma unroll
        for (int ns = 0; ns < 4; ns++) qPs[rb2 + ns * 16 + q15] = f2bf(v[ns] * sc);
        if (q15 == 0) qtc[bh * 1024 + s] = sqrtf(ss / (ss + 1e-6f) + 1.f);
      } else if (mode == 1) {
        const float sc = rsqrtf(ss + 1e-6f);
        const long rb2 = (long)(bh * 1024 + s) * 64;
#pragma unroll
        for (int ns = 0; ns < 4; ns++) kPs[rb2 + ns * 16 + q15] = f2bf(v[ns] * sc);
        if (q15 == 0) ktc[bh * 1024 + s] = sqrtf(ss / (ss + 1e-6f) + 1.f);
      } else {
        const long vb = (long)bh * 81920;
#pragma unroll
        for (int ns = 0; ns < 4; ns++) vT[vb + (long)(1 + ns * 16 + q15) * 1024 + s] = f2bf(v[ns]);
        if (q15 == 0) vT[vb + s] = f2bf(sqrtf(ss + 1.f));
      }
    }
  }
}

// ---------------- 128Mx64N MFMA GEMM, BK=64 -----------------------------
// K mult of 64. EPI: 0 = f32 out (+= if accf), 1 = bf16 out, 2 = gelu bf16
// XCD-swizzled blocks (T1). Split-K via blockIdx.z: K-offset = z*kz elems;
// z=1 writes EPI0 output to Cz1 instead of Cv (no atomics, no races).
template <int EPI, bool SS>
__global__ __launch_bounds__(256) void mfma_gemm(const bf16* __restrict__ A, int lda,
                                                 const bf16* __restrict__ Bw, int ldb, int K,
                                                 const float* __restrict__ bias,
                                                 void* __restrict__ Cv, int ldc, int accf,
                                                 float* __restrict__ tacc,
                                                 int kz, float* __restrict__ Cz1) {
  __shared__ __align__(16) short As[2][128 * 32];
  __shared__ __align__(16) short Bs[2][64 * 32];
  const int tid = threadIdx.x, lane = tid & 63, wv = tid >> 6;
  const int quad = lane >> 4, q15 = lane & 15;
  const int wave_m = wv & 1, wave_n = wv >> 1;
  int bx, by;
  xcd_swz(bx, by);
  const int n0 = bx * 64, m0 = by * 128;
  const long zoff = (long)blockIdx.z * kz;
  const int sa0 = wv * 128 + lane, sa1 = sa0 + 64;
  const int ra0 = sa0 >> 2, ca0 = (sa0 & 3) ^ (ra0 & 3);
  const int ra1 = sa1 >> 2, ca1 = (sa1 & 3) ^ (ra1 & 3);
  const int rb = tid >> 2, cb = (tid & 3) ^ (rb & 3);
  const int kswz = (quad ^ (q15 & 3)) * 8;
  const bf16* pa0 = A + zoff + (long)(m0 + ra0) * lda + ca0 * 8;
  const bf16* pa1 = A + zoff + (long)(m0 + ra1) * lda + ca1 * 8;
  const bf16* pb  = Bw + zoff + (long)(n0 + rb) * ldb + cb * 8;
  f32x4 acc[4][2] = {};
  for (int k0 = 0; k0 < K; k0 += 64) {
#pragma unroll
    for (int p = 0; p < 2; p++) {
      gload16(pa0 + p * 32, As[p] + sa0 * 8);
      gload16(pa1 + p * 32, As[p] + sa1 * 8);
      gload16(pb + p * 32, Bs[p] + tid * 8);
    }
    pa0 += 64; pa1 += 64; pb += 64;
    __syncthreads();
#pragma unroll
    for (int p = 0; p < 2; p++) {
      short8 af[4], bfr[2];
#pragma unroll
      for (int i = 0; i < 4; i++)
        af[i] = *(const short8*)(As[p] + (wave_m * 64 + i * 16 + q15) * 32 + kswz);
#pragma unroll
      for (int i = 0; i < 2; i++)
        bfr[i] = *(const short8*)(Bs[p] + (wave_n * 32 + i * 16 + q15) * 32 + kswz);
#pragma unroll
      for (int mi = 0; mi < 4; mi++)
#pragma unroll
        for (int ni = 0; ni < 2; ni++)
          acc[mi][ni] = __builtin_amdgcn_mfma_f32_16x16x32_bf16(af[mi], bfr[ni], acc[mi][ni], 0, 0, 0);
    }
    __syncthreads();
  }
#pragma unroll
  for (int mi = 0; mi < 4; mi++) {
#pragma unroll
    for (int r = 0; r < 4; r++) {
      const int m = m0 + wave_m * 64 + mi * 16 + quad * 4 + r;
      float s2 = 0.f;
#pragma unroll
      for (int ni = 0; ni < 2; ni++) {
        const int n = n0 + wave_n * 32 + ni * 16 + q15;
        float v = acc[mi][ni][r] + (bias ? bias[n] : 0.f);
        const long idx = (long)m * ldc + n;
        if (EPI == 0) {
          float* Cf = (blockIdx.z && Cz1) ? Cz1 : (float*)Cv;
          if (accf) v += Cf[idx];
          Cf[idx] = v;
        } else if (EPI == 1) {
          ((bf16*)Cv)[idx] = f2bf(v);
        } else {
          v = gelu_f(v);
          ((bf16*)Cv)[idx] = f2bf(v);
        }
        if (SS) s2 += v * v;
      }
      if (SS) {
        s2 += __shfl_xor(s2, 1);
        s2 += __shfl_xor(s2, 2);
        s2 += __shfl_xor(s2, 4);
        s2 += __shfl_xor(s2, 8);
        if (q15 == 0) atomicAdd(tacc + m, s2);
      }
    }
  }
}

// ---------------- MFMA flash attention (static max, XCD swizzle) --------
// mcat layout: (R, LD_), head h at cols [h*66, h*66+65], pads zeroed
__global__ __launch_bounds__(256) void attn_kernel(const bf16* __restrict__ qPs,
                                                   const float* __restrict__ qtc,
                                                   const bf16* __restrict__ kPs,
                                                   const float* __restrict__ ktc,
                                                   const bf16* __restrict__ vT,
                                                   const float* __restrict__ scalf,
                                                   bf16* __restrict__ mcat) {
  __shared__ __align__(16) short kbuf[64 * 72];
  __shared__ __align__(16) short vbuf[80 * 72];
  __shared__ __align__(16) short pbuf[64 * 72];
  __shared__ float tkl[64];
  const int tid = threadIdx.x, lane = tid & 63, wv = tid >> 6;
  const int quad = lane >> 4, q15 = lane & 15;
  const int id = blockIdx.x;
  const int cxd = id & 7, jj_ = id >> 3;
  const int bh = cxd * 8 + (jj_ & 7), qt_ = jj_ >> 3;
  const float inv_scale = 1.f / scalf[0];
  const long qrow = (long)(bh * 1024 + qt_ * 64 + wv * 16 + q15) * 64;
  const short8 aq0 = *(const short8*)(qPs + qrow + quad * 8);
  const short8 aq1 = *(const short8*)(qPs + qrow + 32 + quad * 8);
  float tqr[4];
#pragma unroll
  for (int r = 0; r < 4; r++) tqr[r] = qtc[bh * 1024 + qt_ * 64 + wv * 16 + quad * 4 + r];
  f32x4 out[5];
#pragma unroll
  for (int mt = 0; mt < 5; mt++) out[mt] = f32x4{0, 0, 0, 0};
  float lip[4] = {0.f, 0.f, 0.f, 0.f};
  const int srcl = (q15 >> 2) << 4;
  for (int kt = 0; kt < 16; kt++) {
    __syncthreads();
#pragma unroll
    for (int c = 0; c < 2; c++) {
      const int id2 = c * 256 + tid, row = id2 >> 3, off = id2 & 7;
      *(uint4*)(kbuf + row * 72 + off * 8) =
          *(const uint4*)(kPs + (long)(bh * 1024 + kt * 64 + row) * 64 + off * 8);
    }
#pragma unroll
    for (int c = 0; c < 3; c++) {
      const int id2 = c * 256 + tid;
      if (id2 < 640) {
        const int row = id2 >> 3, off = id2 & 7;
        *(uint4*)(vbuf + row * 72 + off * 8) =
            *(const uint4*)(vT + (long)bh * 81920 + (long)row * 1024 + kt * 64 + off * 8);
      }
    }
    if (tid < 64) tkl[tid] = ktc[bh * 1024 + kt * 64 + tid];
    __syncthreads();
    f32x4 sacc[4] = {f32x4{0,0,0,0}, f32x4{0,0,0,0}, f32x4{0,0,0,0}, f32x4{0,0,0,0}};
#pragma unroll
    for (int ns = 0; ns < 4; ns++) {
      short8 b0 = *(const short8*)(kbuf + (ns * 16 + q15) * 72 + quad * 8);
      short8 b1 = *(const short8*)(kbuf + (ns * 16 + q15) * 72 + 32 + quad * 8);
      sacc[ns] = __builtin_amdgcn_mfma_f32_16x16x32_bf16(aq0, b0, sacc[ns], 0, 0, 0);
      sacc[ns] = __builtin_amdgcn_mfma_f32_16x16x32_bf16(aq1, b1, sacc[ns], 0, 0, 0);
    }
#pragma unroll
    for (int ns = 0; ns < 4; ns++) {
      const float tk = tkl[ns * 16 + q15];
#pragma unroll
      for (int r = 0; r < 4; r++) {
        const float pv = __expf((2.f + 2.f * (sacc[ns][r] - tqr[r] * tk)) * inv_scale);
        lip[r] += pv;
        pbuf[(wv * 16 + quad * 4 + r) * 72 + ns * 16 + q15] = (short)bf2s(pv);
      }
    }
#pragma unroll
    for (int mt = 0; mt < 5; mt++)
#pragma unroll
      for (int kc = 0; kc < 2; kc++) {
        short8 av = *(const short8*)(vbuf + (mt * 16 + q15) * 72 + kc * 32 + quad * 8);
        short8 bp = *(const short8*)(pbuf + (wv * 16 + q15) * 72 + kc * 32 + quad * 8);
        out[mt] = __builtin_amdgcn_mfma_f32_16x16x32_bf16(av, bp, out[mt], 0, 0, 0);
      }
  }
  {
#pragma unroll
    for (int o = 8; o; o >>= 1)
#pragma unroll
      for (int r = 0; r < 4; r++) lip[r] += __shfl_xor(lip[r], o);
    float linv[4];
#pragma unroll
    for (int r = 0; r < 4; r++) linv[r] = 1.f / lip[r];
    const float t0 = __shfl(linv[0], srcl), t1 = __shfl(linv[1], srcl);
    const float t2 = __shfl(linv[2], srcl), t3 = __shfl(linv[3], srcl);
    const int rr = q15 & 3;
    const float lv = (rr == 0) ? t0 : (rr == 1) ? t1 : (rr == 2) ? t2 : t3;
#pragma unroll
    for (int mt = 0; mt < 5; mt++)
#pragma unroll
      for (int j = 0; j < 4; j++) out[mt][j] *= lv;
  }
  float part = 0.f;
#pragma unroll
  for (int mt = 0; mt < 5; mt++)
#pragma unroll
    for (int j = 0; j < 4; j++) {
      const int e = mt * 16 + quad * 4 + j;
      const float vv = out[mt][j] * out[mt][j];
      part += (e == 0) ? vv : -vv;
    }
  part += __shfl_xor(part, 16);
  part += __shfl_xor(part, 32);
  const float dinv = rsqrtf(fmaxf(part, 1e-6f));
  __syncthreads();
  short* obuf = vbuf;
  const int qrow_l = wv * 16 + q15;
#pragma unroll
  for (int mt = 0; mt < 5; mt++)
#pragma unroll
    for (int j = 0; j < 4; j++) {
      const int e = mt * 16 + quad * 4 + j;
      if (e <= 64) obuf[qrow_l * 72 + e] = (short)bf2s(out[mt][j] * dinv);
    }
  if (quad == 1) obuf[qrow_l * 72 + 65] = 0;
  __syncthreads();
  const int b = bh >> 4, h = bh & 15;
  const long outbase = ((long)b * 1024 + qt_ * 64) * LD_ + h * 66;
  for (int i = tid; i < 64 * 33; i += 256) {
    const int row = i / 33, p = i - row * 33;
    *(unsigned*)(mcat + outbase + (long)row * LD_ + p * 2) =
        *(const unsigned*)(obuf + row * 72 + p * 2);
  }
  if (h == 15) {
    const long zb = ((long)b * 1024 + qt_ * 64) * LD_ + 1056;
    for (int i = tid; i < 64 * 16; i += 256) {
      const int row = i >> 4, p = i & 15;
      *(unsigned*)(mcat + zb + (long)row * LD_ + p * 2) = 0u;
    }
  }
}

// ---------------- FF tail ------------------------------------------------
__global__ __launch_bounds__(256) void final_fix_kernel(const float* __restrict__ t_acc,
                                                        const float* __restrict__ w2r0,
                                                        const float* __restrict__ b2f,
                                                        float* __restrict__ mlp) {
  const int m = blockIdx.x;
  const float t = sqrtf(1.f + t_acc[m]);
  float* row = mlp + (long)m * 1024;
  for (int n = threadIdx.x; n < 1024; n += 256) row[n] += t * w2r0[n] + b2f[n];
}

// big path: also folds in the split-K z=1 partial (part1)
__global__ __launch_bounds__(256) void final_fix_big(const bf16* __restrict__ hh,
                                                     const float* __restrict__ w2r0,
                                                     const float* __restrict__ b2f,
                                                     const float* __restrict__ part1,
                                                     float* __restrict__ mlp) {
  __shared__ float red[4];
  const int m = blockIdx.x;
  const uint4* r4 = (const uint4*)(hh + (long)m * 4096);
  float ss = 0.f;
  for (int i = threadIdx.x; i < 512; i += 256) {
    const uint4 u = r4[i];
    const unsigned a[4] = {u.x, u.y, u.z, u.w};
#pragma unroll
    for (int j = 0; j < 4; j++) {
      const float lo = bfu_lo(a[j]), hi = bfu_hi(a[j]);
      ss += lo * lo + hi * hi;
    }
  }
  ss = bred_f(ss, red);
  const float t = sqrtf(1.f + ss);
  float* row = mlp + (long)m * 1024;
  const float* prow = part1 + (long)m * 1024;
  for (int n = threadIdx.x; n < 1024; n += 256)
    row[n] += prow[n] + t * w2r0[n] + b2f[n];
}

// ---------------- fused residual+project+layernorm (proj1 + ln2) ---------
// x2 = project(x + w*to_manifold(araw));  hbuf = hyp_layernorm(x2) (padded)
__global__ __launch_bounds__(256) void proj_ln_kernel(
    const void* __restrict__ x, const bf16* __restrict__ c,
    const float* __restrict__ scalf, int widx,
    const void* __restrict__ g, const void* __restrict__ b,
    bf16* __restrict__ x2, bf16* __restrict__ hbuf, const int* __restrict__ flag) {
  const int isbf = flag[0];
  __shared__ double redd[4];
  __shared__ float redf[4];
  const long bx = (long)blockIdx.x * 1025;
  const long bc = (long)blockIdx.x * 1024;
  const long ob = (long)blockIdx.x * LD_;
  const int tid = threadIdx.x;
  const double w = (double)scalf[widx];
  const float x0 = ldu(x, bx, isbf);
  float xs[4], cv[4];
#pragma unroll
  for (int i = 0; i < 4; i++) {
    xs[i] = ldu(x, bx + 1 + tid * 4 + i, isbf);
    cv[i] = bf2f(c[bc + tid * 4 + i]);
  }
  double cc = 0.0, xx = 0.0, xc = 0.0, sx = 0.0, sc_ = 0.0;
#pragma unroll
  for (int i = 0; i < 4; i++) {
    cc += (double)cv[i] * cv[i];
    xx += (double)xs[i] * xs[i];
    xc += (double)xs[i] * cv[i];
    sx += (double)xs[i];
    sc_ += (double)cv[i];
  }
  cc = bred_d(cc, redd);
  xx = bred_d(xx, redd);
  xc = bred_d(xc, redd);
  sx = bred_d(sx, redd);
  sc_ = bred_d(sc_, redd);
  const double t   = sqrt(1.0 + cc);
  const double lxx = (double)x0 * x0 - xx;
  const double xm  = -(double)x0 * t + xc;
  double d2 = lxx + w * w - 2.0 * w * xm;
  if (d2 < 1e-6) d2 = 1e-6;
  const double dinv = 1.0 / sqrt(d2);
  // write x2 (bf16, ld 1025)
  if (tid == 0) x2[bx] = f2bf((float)(((double)x0 + w * t) * dinv));
  float z[4];
#pragma unroll
  for (int i = 0; i < 4; i++) {
    z[i] = (float)(((double)xs[i] + w * cv[i]) * dinv);
    x2[bx + 1 + tid * 4 + i] = f2bf(z[i]);
  }
  // LN stats from analytic sums: sum z = dinv*(sx + w*sc_); sum z^2 = dinv^2*(xx+2w*xc+w^2*cc)
  const float sumz  = (float)((sx + w * sc_) * dinv);
  const float sumsq = (float)((xx + 2.0 * w * xc + w * w * cc) * dinv * dinv);
  const float mu  = sumz * (1.f / 1024.f);
  const float var = sumsq * (1.f / 1024.f) - mu * mu;
  const float rs  = rsqrtf(var + 1e-5f);
  float n[4], ns = 0.f;
#pragma unroll
  for (int i = 0; i < 4; i++) {
    const int e = tid * 4 + i;
    n[i] = (z[i] - mu) * rs * ldu(g, e, isbf) + ldu(b, e, isbf);
    ns += n[i] * n[i];
  }
  ns = bred_f(ns, redf);
  if (tid == 0) hbuf[ob] = f2bf(sqrtf(ns + 1.f));
#pragma unroll
  for (int i = 0; i < 4; i++) hbuf[ob + 1 + tid * 4 + i] = f2bf(n[i]);
  if (tid < 63) hbuf[ob + 1025 + tid] = f2bf(0.f);
}

// ---------------- residual + project (stable identity, f64 dots) ---------
__global__ __launch_bounds__(256) void res_project_kernel(
    const void* __restrict__ x, int xtag, const void* __restrict__ c, int ctag,
    const float* __restrict__ scalf, int widx, void* __restrict__ out, int otag,
    const int* __restrict__ flag) {
  const int isbf = flag[0];
  const int xb = (xtag == 2) ? isbf : xtag;
  const int cb2 = (ctag == 2) ? isbf : ctag;
  const int ob = (otag == 2) ? isbf : otag;
  __shared__ double red[4];
  const long bx = (long)blockIdx.x * 1025;
  const long bc = (long)blockIdx.x * 1024;
  const int tid = threadIdx.x;
  const double w = (double)scalf[widx];
  const float x0 = ldu(x, bx, xb);
  float xs[4], cv[4];
#pragma unroll
  for (int i = 0; i < 4; i++) {
    xs[i] = ldu(x, bx + 1 + tid * 4 + i, xb);
    cv[i] = ldu(c, bc + tid * 4 + i, cb2);
  }
  double cc = 0.0, xx = 0.0, xc = 0.0;
#pragma unroll
  for (int i = 0; i < 4; i++) {
    cc += (double)cv[i] * cv[i];
    xx += (double)xs[i] * xs[i];
    xc += (double)xs[i] * cv[i];
  }
  cc = bred_d(cc, red);
  xx = bred_d(xx, red);
  xc = bred_d(xc, red);
  const double t   = sqrt(1.0 + cc);
  const double lxx = (double)x0 * x0 - xx;
  const double xm  = -(double)x0 * t + xc;
  double d2 = lxx + w * w - 2.0 * w * xm;
  if (d2 < 1e-6) d2 = 1e-6;
  const double dinv = 1.0 / sqrt(d2);
  if (tid == 0) stu(out, bx, (float)(((double)x0 + w * t) * dinv), ob);
#pragma unroll
  for (int i = 0; i < 4; i++)
    stu(out, bx + 1 + tid * 4 + i, (float)(((double)xs[i] + w * cv[i]) * dinv), ob);
}

extern "C" void kernel_launch(void* const* d_in, const int* in_sizes, int n_in,
                              void* d_out, int out_size, void* d_ws, size_t ws_size,
                              hipStream_t stream) {
  char* w = (char*)d_ws;
  char* bias_base = w + OFF_BIAS;
  int* flag = (int*)(bias_base + FLAG);
  float* tacc = (float*)(bias_base + TACC);
  const float* scalf = (const float*)(bias_base + SCLF);
  const bool big = ws_size >= (size_t)92 * MBL;
  char* mlp_off = big ? (w + OFF_MLPB) : (w + OFF_MLPF);

  detect_kernel<<<1, 64, 0, stream>>>((const unsigned*)d_in[3], flag);
  zero16_kernel<<<4, 256, 0, stream>>>((uint4*)tacc, 1024);

  // all prep (scalars + 4 weight transposes + ln1) in one dispatch
  mega_prep<<<7593, 256, 0, stream>>>(
      d_in[0], d_in[1], d_in[2], d_in[3], d_in[4], d_in[5], d_in[6], d_in[7], d_in[8],
      d_in[9], d_in[10], d_in[11], d_in[12], d_in[13], d_in[14], d_in[15], d_in[18],
      d_in[19], d_in[20], d_in[21], d_in[22], bias_base, (bf16*)(w + OFF_WQKVT),
      (bf16*)(w + OFF_WOT), (bf16*)(w + OFF_W1T), (bf16*)(w + OFF_W2T),
      (bf16*)(w + OFF_XNB), flag);

  // QKV on the 256x256 deep-pipelined GEMM (N=3072 -> 12 col-blocks)
  gemm_qkv256<<<dim3(12, 16), 512, 0, stream>>>(
      (const bf16*)(w + OFF_XNB), (const bf16*)(w + OFF_WQKVT), bias_base,
      (bf16*)(w + OFF_QPS), (float*)(w + OFF_QT), (bf16*)(w + OFF_KPS),
      (float*)(w + OFF_KT), (bf16*)(w + OFF_VT));
  attn_kernel<<<1024, 256, 0, stream>>>(
      (const bf16*)(w + OFF_QPS), (const float*)(w + OFF_QT), (const bf16*)(w + OFF_KPS),
      (const float*)(w + OFF_KT), (const bf16*)(w + OFF_VT), scalf, (bf16*)(w + OFF_MCAT));
  mfma_gemm<1, false><<<dim3(16, 32), 256, 0, stream>>>(
      (const bf16*)(w + OFF_MCAT), LD_, (const bf16*)(w + OFF_WOT), LD_, LD_,
      (const float*)(bias_base + BOF), w + OFF_ARAW, 1024, 0, nullptr, 0, nullptr);
  // fused proj1 + ln2
  proj_ln_kernel<<<R_, 256, 0, stream>>>(d_in[0], (const bf16*)(w + OFF_ARAW), scalf, 2,
                                         d_in[16], d_in[17], (bf16*)(w + OFF_X2),
                                         (bf16*)(w + OFF_HBUF), flag);
  if (big) {
    // W1 GEMM (4096x4096xK=1088) on the 256x256 pipeline: 256 blocks = 1/CU
    gemm256<2><<<dim3(16, 16), 512, 0, stream>>>(
        (const bf16*)(w + OFF_HBUF), LD_, (const bf16*)(w + OFF_W1T), LD_, LD_,
        (const float*)(bias_base + B1F), w + OFF_HHBIG, 4096, 0);
    // W2 (4096x1024xK=4096), split-K=2 via grid z: z=0 -> mlp, z=1 -> part1.
    // 1024 blocks = 4/CU (occupancy was the r7-measured limiter at 512).
    mfma_gemm<0, false><<<dim3(16, 32, 2), 256, 0, stream>>>(
        (const bf16*)(w + OFF_HHBIG), 4096, (const bf16*)(w + OFF_W2T), 4096, 2048,
        nullptr, mlp_off, 1024, 0, nullptr, 2048, (float*)(w + OFF_PART1));
    final_fix_big<<<R_, 256, 0, stream>>>((const bf16*)(w + OFF_HHBIG),
                                          (const float*)(bias_base + W2R0),
                                          (const float*)(bias_base + B2F),
                                          (const float*)(w + OFF_PART1),
                                          (float*)mlp_off);
  } else {
    for (int c = 0; c < 4; c++) {
      mfma_gemm<2, true><<<dim3(16, 32), 256, 0, stream>>>(
          (const bf16*)(w + OFF_HBUF), LD_, (const bf16*)(w + OFF_W1T) + (long)c * 1024 * LD_,
          LD_, LD_, (const float*)(bias_base + B1F) + c * 1024, w + OFF_HHC, 1024, 0, tacc,
          0, nullptr);
      mfma_gemm<0, false><<<dim3(16, 32), 256, 0, stream>>>(
          (const bf16*)(w + OFF_HHC), 1024, (const bf16*)(w + OFF_W2T) + c * 1024, 4096, 1024,
          nullptr, mlp_off, 1024, c > 0 ? 1 : 0, nullptr, 0, nullptr);
    }
    final_fix_kernel<<<R_, 256, 0, stream>>>(tacc, (const float*)(bias_base + W2R0),
                                             (const float*)(bias_base + B2F),
                                             (float*)mlp_off);
  }
  res_project_kernel<<<R_, 256, 0, stream>>>(w + OFF_X2, 1, mlp_off, 0, scalf, 3,
                                             d_out, 2, flag);
}